// Round 10
// baseline (645.542 us; speedup 1.0000x reference)
//
#include <hip/hip_runtime.h>
#include <hip/hip_bf16.h>
#include <cstddef>

typedef __attribute__((ext_vector_type(8))) short bf16x8;
typedef __attribute__((ext_vector_type(4))) float f32x4;

// ---------------------------------------------------------------------------
// Workspace byte offsets (x1b/x2b padded layouts for DMA-friendly conv chain)
// ---------------------------------------------------------------------------
static constexpr size_t OFF_X1B   = 0;          // bf16 [2048][20][20][40] (pad 40)
static constexpr size_t OFF_X2B   = 65536000;   // bf16 [2048][9][9][72]  (pad 72)
static constexpr size_t OFF_X3B   = 89423872;   // bf16 [2048][3136] k=sp*64+ci
static constexpr size_t OFF_FEATB = 102268928;  // bf16 [2048][512]
static constexpr size_t OFF_W2B   = 104366080;  // bf16 [64][512]
static constexpr size_t OFF_W3B   = 104431616;  // bf16 [64][576]
static constexpr size_t OFF_FCWB  = 104505344;  // bf16 [512][3136]
static constexpr size_t OFF_WIHB  = 107716608;  // bf16 [1024][512]
static constexpr size_t OFF_GX    = 108765184;  // f32 [2048][1024]
static constexpr size_t OFF_HSEQ  = 117153792;  // f32 [2048][256]
static constexpr size_t OFF_W1B   = 119250944;  // bf16 [32][256]
static constexpr size_t OFF_WHHB  = 119267328;  // bf16 [1024][256]
static constexpr size_t OFF_ORDB  = 119791616;  // int[2048]
static constexpr size_t OFF_ORDT0 = 119799808;  // int[2048]
static constexpr size_t OFF_ORDLEN= 119808000;  // int[2048]
static constexpr size_t OFF_NSEG  = 119816192;  // int[1]
static constexpr size_t OFF_FCPART= 119824384;  // f32 [8][2048][512]

__device__ __forceinline__ float sigmoidf_(float x) {
  return 1.0f / (1.0f + __expf(-x));
}
__device__ __forceinline__ float tanhf_(float x) {
  return 1.0f - 2.0f / (__expf(2.0f * x) + 1.0f);
}
__device__ __forceinline__ short f2bfs(float x) {
  union { __hip_bfloat16 b; short s; } cv;
  cv.b = __float2bfloat16(x);
  return cv.s;
}
// async global->LDS DMA, 16B per lane. LDS dest = wave-uniform base + lane*16;
// global src is per-lane. Drained by the vmcnt(0) the compiler emits before
// s_barrier (__syncthreads).
__device__ __forceinline__ void dma16(const void* g, void* l) {
  __builtin_amdgcn_global_load_lds(
      (const __attribute__((address_space(1))) unsigned int*)g,
      (__attribute__((address_space(3))) unsigned int*)l, 16, 0, 0);
}

// ---------------------------------------------------------------------------
// Prep + plan merged: blocks 0..9647 do weight convert/reorder; block 9648
// does the segment planning (saves one launch + dependency edge).
// ---------------------------------------------------------------------------
__global__ __launch_bounds__(256) void prep_kernel(
    const float* __restrict__ c1w, const float* __restrict__ c2w,
    const float* __restrict__ c3w, const float* __restrict__ fcw,
    const float* __restrict__ wih, const float* __restrict__ whh,
    __hip_bfloat16* __restrict__ w1b,
    __hip_bfloat16* __restrict__ w2b, __hip_bfloat16* __restrict__ w3b,
    __hip_bfloat16* __restrict__ fcwb, __hip_bfloat16* __restrict__ wihb,
    __hip_bfloat16* __restrict__ whhb,
    const float* __restrict__ starts, int* __restrict__ ord_b,
    int* __restrict__ ord_t0, int* __restrict__ ord_len,
    int* __restrict__ nseg_out) {
  const int tid = threadIdx.x;
  if (blockIdx.x == 9648) {
    // ---- plan body ----
    __shared__ float s_starts[2048];
    __shared__ int s_t0[2048];
    __shared__ int s_len[2048];
    __shared__ int cnt[16];
    __shared__ int hist[132];
    __shared__ int off[132];
    {
      float4* d = (float4*)s_starts;
      const float4* s = (const float4*)starts;
#pragma unroll
      for (int i = 0; i < 2; ++i) d[tid + i * 256] = s[tid + i * 256];
    }
    if (tid < 132) hist[tid] = 0;
    __syncthreads();
    if (tid < 16) {
      int b = tid, c = 0;
      for (int t = 0; t < 128; ++t) {
        float s = s_starts[t * 16 + b];
        if (t == 0 || s != 0.0f) {
          if (c > 0) s_len[b * 128 + c - 1] = t - s_t0[b * 128 + c - 1];
          s_t0[b * 128 + c] = t;
          ++c;
        }
      }
      s_len[b * 128 + c - 1] = 128 - s_t0[b * 128 + c - 1];
      cnt[b] = c;
    }
    __syncthreads();
    for (int idx = tid; idx < 2048; idx += 256) {
      int b = idx >> 7, i = idx & 127;
      if (i < cnt[b]) atomicAdd(&hist[s_len[idx]], 1);
    }
    __syncthreads();
    if (tid == 0) {
      int running = 0;
      for (int L = 128; L >= 1; --L) { off[L] = running; running += hist[L]; }
      *nseg_out = running;
    }
    __syncthreads();
    for (int idx = tid; idx < 2048; idx += 256) {
      int b = idx >> 7, i = idx & 127;
      if (i < cnt[b]) {
        int len = s_len[idx];
        int pos = atomicAdd(&off[len], 1);
        ord_b[pos] = b;
        ord_t0[pos] = s_t0[idx];
        ord_len[pos] = len;
      }
    }
    return;
  }
  int i = blockIdx.x * 256 + tid;
  if (i < 32768) {                          // w2b: k=(ky*4+kx)*32+ci
    int o = i >> 9, k = i & 511;
    int pos = k >> 5, ci = k & 31;
    int ky = pos >> 2, kx = pos & 3;
    w2b[i] = __float2bfloat16(c2w[o * 512 + ci * 16 + ky * 4 + kx]);
  } else if (i < 69632) {                   // w3b: k=(ky*3+kx)*64+ci
    int j = i - 32768;
    int o = j / 576, k = j - o * 576;
    int pos = k >> 6, ci = k & 63;
    int ky = pos / 3, kx = pos - ky * 3;
    w3b[j] = __float2bfloat16(c3w[o * 576 + ci * 9 + ky * 3 + kx]);
  } else if (i < 1675264) {                 // fcwb: k=sp*64+ci
    int j = i - 69632;
    int o = j / 3136, k = j - o * 3136;
    int sp = k >> 6, ci = k & 63;
    fcwb[j] = __float2bfloat16(fcw[o * 3136 + ci * 49 + sp]);
  } else if (i < 2199552) {                 // wihb: native
    int j = i - 1675264;
    wihb[j] = __float2bfloat16(wih[j]);
  } else if (i < 2461696) {                 // whhb: straight copy [1024][256]
    int j = i - 2199552;
    whhb[j] = __float2bfloat16(whh[j]);
  } else if (i < 2469888) {                 // w1b: k=ky*32+ci*8+kx, *(1/255)
    int j = i - 2461696;
    int oc = j >> 8, k = j & 255;
    int ky = k >> 5, rem = k & 31;
    int ci = rem >> 3, kx = rem & 7;
    w1b[j] = __float2bfloat16(c1w[oc * 256 + ci * 64 + ky * 8 + kx] * (1.0f / 255.0f));
  }
}

// ---------------------------------------------------------------------------
// conv1 v6: 512 threads (8 waves). DMA split 8 ways (2 waves per channel
// region); frag loop f += 8 (max 2 frags/wave, was 4). LDS unchanged ->
// still 2 blocks/CU. Output: padded CL [20][20][40].
// ---------------------------------------------------------------------------
__global__ __launch_bounds__(512, 4) void conv1_dma(
    const float* __restrict__ obs, const __hip_bfloat16* __restrict__ w1b,
    const float* __restrict__ bias1, __hip_bfloat16* __restrict__ x1b) {
  constexpr int LDW = 264;
  __shared__ __align__(16) float imgf[15552];          // 4 regions x 3840 + pad
  __shared__ __align__(16) __hip_bfloat16 Ws[32 * LDW];
  const int tid = threadIdx.x;
  const int wv = tid >> 6, l = tid & 63;
  const int lane16 = l & 15, quad = l >> 4;
  const int n = blockIdx.x >> 1, h = blockIdx.x & 1;

  for (int i = tid; i < 1024; i += 512) {
    const int r = i >> 5, c = (i & 31) * 8;
    *(uint4*)&Ws[r * LDW + c] = *(const uint4*)&w1b[r * 256 + c];
  }
  {
    // waves (2c, 2c+1) stage channel region c: 44 rows x 84 f32 = 14784 B
    const int reg = wv >> 1, half = wv & 1;
    const char* gbase = (const char*)(obs + (size_t)n * 28224 + reg * 7056 + h * 3360);
    char* lbase = (char*)imgf + reg * 15360;
    const int k0 = half ? 8 : 0, k1 = half ? 15 : 8;
    for (int k = k0; k < k1; ++k) {
      int off = k * 1024 + l * 16;
      if (off >= 14784) off = 0;     // tail lanes: clamp src, dest lands in pad
      dma16(gbase + off, lbase + k * 1024);
    }
  }
  __syncthreads();   // compiler drains vmcnt(0): DMA complete

  const float bb0 = bias1[lane16];
  const float bb1 = bias1[16 + lane16];
  for (int f = wv; f < 13; f += 8) {
    const int sp = f * 16 + lane16;              // 0..207 (valid < 200)
    const int oy = sp / 20, ox = sp - oy * 20;
    const float* ab = &imgf[quad * 3840 + (oy * 4) * 84 + ox * 4];
    f32x4 acc0 = {}, acc1 = {};
#pragma unroll
    for (int s = 0; s < 8; ++s) {
      const f32x4 lo = *(const f32x4*)(ab + s * 84);
      const f32x4 hi = *(const f32x4*)(ab + s * 84 + 4);
      bf16x8 a;
      a[0] = f2bfs(lo[0]); a[1] = f2bfs(lo[1]); a[2] = f2bfs(lo[2]); a[3] = f2bfs(lo[3]);
      a[4] = f2bfs(hi[0]); a[5] = f2bfs(hi[1]); a[6] = f2bfs(hi[2]); a[7] = f2bfs(hi[3]);
      const bf16x8 b0 = *(const bf16x8*)&Ws[lane16 * LDW + s * 32 + quad * 8];
      const bf16x8 b1 = *(const bf16x8*)&Ws[(16 + lane16) * LDW + s * 32 + quad * 8];
      acc0 = __builtin_amdgcn_mfma_f32_16x16x32_bf16(a, b0, acc0, 0, 0, 0);
      acc1 = __builtin_amdgcn_mfma_f32_16x16x32_bf16(a, b1, acc1, 0, 0, 0);
    }
    const size_t base = (size_t)n * 16000 + (size_t)(h * 200) * 40;
#pragma unroll
    for (int r = 0; r < 4; ++r) {
      const int ml = f * 16 + quad * 4 + r;
      if (ml < 200) {
        x1b[base + ml * 40 + lane16] = __float2bfloat16(fmaxf(acc0[r] + bb0, 0.f));
        x1b[base + ml * 40 + 16 + lane16] = __float2bfloat16(fmaxf(acc1[r] + bb1, 0.f));
      }
    }
  }
}

// ---------------------------------------------------------------------------
// conv2 v6: 512 threads (8 waves). DMA split 8 ways (4 chunks/wave);
// 6 frags over 8 waves -> max 1 frag/wave (was 2). LDS unchanged -> 2/CU.
// ---------------------------------------------------------------------------
__global__ __launch_bounds__(512, 4) void conv2_dma(
    const __hip_bfloat16* __restrict__ x1b, const __hip_bfloat16* __restrict__ w2b,
    const float* __restrict__ bias, __hip_bfloat16* __restrict__ x2b) {
  constexpr int LDW = 520;
  __shared__ __align__(16) __hip_bfloat16 img[24 * 800];   // [24][20][40]
  __shared__ __align__(16) __hip_bfloat16 Ws[32 * LDW];
  const int tid = threadIdx.x;
  const int wv = tid >> 6, l = tid & 63;
  const int lane16 = l & 15, quad = l >> 4;
  const int n = blockIdx.x >> 1, nh = blockIdx.x & 1;

  for (int i = tid; i < 2048; i += 512) {
    const int r = i >> 6, c = (i & 63) * 8;
    *(uint4*)&Ws[r * LDW + c] = *(const uint4*)&w2b[(nh * 32 + r) * 512 + c];
  }
  {
    const char* g = (const char*)(x1b + (size_t)n * 16000);
    char* lb = (char*)img;
    for (int i = 0; i < 4; ++i) {
      const int k = wv * 4 + i;
      int off = k * 1024 + l * 16;
      if (off >= 32000) off = 0;
      dma16(g + off, lb + k * 1024);
    }
  }
  __syncthreads();

  const int colg = nh * 32;
  const float bb0 = bias[colg + lane16];
  const float bb1 = bias[colg + 16 + lane16];
  for (int f = wv; f < 6; f += 8) {
    const int sp = f * 16 + lane16;              // 0..95 (valid < 81)
    const int oy = sp / 9, ox = sp - oy * 9;
    const __hip_bfloat16* ab = &img[((oy * 2) * 20 + ox * 2) * 40 + quad * 8];
    f32x4 acc0 = {}, acc1 = {};
#pragma unroll
    for (int s = 0; s < 16; ++s) {
      const int ky = s >> 2, kx = s & 3;
      const bf16x8 a = *(const bf16x8*)(ab + (ky * 20 + kx) * 40);
      const bf16x8 b0 = *(const bf16x8*)&Ws[lane16 * LDW + s * 32 + quad * 8];
      const bf16x8 b1 = *(const bf16x8*)&Ws[(16 + lane16) * LDW + s * 32 + quad * 8];
      acc0 = __builtin_amdgcn_mfma_f32_16x16x32_bf16(a, b0, acc0, 0, 0, 0);
      acc1 = __builtin_amdgcn_mfma_f32_16x16x32_bf16(a, b1, acc1, 0, 0, 0);
    }
#pragma unroll
    for (int r = 0; r < 4; ++r) {
      const int ml = f * 16 + quad * 4 + r;
      if (ml < 81) {
        const size_t o = (size_t)n * 5832 + (size_t)ml * 72 + colg;
        x2b[o + lane16] = __float2bfloat16(fmaxf(acc0[r] + bb0, 0.f));
        x2b[o + 16 + lane16] = __float2bfloat16(fmaxf(acc1[r] + bb1, 0.f));
      }
    }
  }
}

// ---------------------------------------------------------------------------
// conv3 v5 (unchanged): per-image x col-half blocks, 3 blocks/CU.
// ---------------------------------------------------------------------------
__global__ __launch_bounds__(256, 3) void conv3_dma(
    const __hip_bfloat16* __restrict__ x2b, const __hip_bfloat16* __restrict__ w3b,
    const float* __restrict__ bias, __hip_bfloat16* __restrict__ x3b) {
  constexpr int LDW = 584;
  __shared__ __align__(16) __hip_bfloat16 img[12 * 648];   // [12][9][72]
  __shared__ __align__(16) __hip_bfloat16 Ws[32 * LDW];
  const int tid = threadIdx.x;
  const int wv = tid >> 6, l = tid & 63;
  const int lane16 = l & 15, quad = l >> 4;
  const int n = blockIdx.x >> 1, nh = blockIdx.x & 1;

  for (int i = tid; i < 2304; i += 256) {
    const int r = i / 72, c = (i - r * 72) * 8;
    *(uint4*)&Ws[r * LDW + c] = *(const uint4*)&w3b[(nh * 32 + r) * 576 + c];
  }
  {
    const char* g = (const char*)(x2b + (size_t)n * 5832);
    char* lb = (char*)img;
    for (int i = 0; i < 3; ++i) {
      const int k = wv * 3 + i;
      int off = k * 1024 + l * 16;
      if (off >= 11664) off = 0;
      dma16(g + off, lb + k * 1024);
    }
  }
  __syncthreads();

  const int colg = nh * 32;
  const float bb0 = bias[colg + lane16];
  const float bb1 = bias[colg + 16 + lane16];
  {
    const int f = wv;                            // exactly 1 frag per wave
    const int sp = f * 16 + lane16;              // 0..63 (valid < 49)
    const int oy = sp / 7, ox = sp - oy * 7;
    const __hip_bfloat16* ab = &img[(oy * 9 + ox) * 72 + quad * 8];
    f32x4 acc0 = {}, acc1 = {};
#pragma unroll
    for (int s = 0; s < 18; ++s) {
      const int pos = s >> 1, half = s & 1;
      const int ky = pos / 3, kx = pos - ky * 3;
      const bf16x8 a = *(const bf16x8*)(ab + (ky * 9 + kx) * 72 + half * 32);
      const bf16x8 b0 = *(const bf16x8*)&Ws[lane16 * LDW + s * 32 + quad * 8];
      const bf16x8 b1 = *(const bf16x8*)&Ws[(16 + lane16) * LDW + s * 32 + quad * 8];
      acc0 = __builtin_amdgcn_mfma_f32_16x16x32_bf16(a, b0, acc0, 0, 0, 0);
      acc1 = __builtin_amdgcn_mfma_f32_16x16x32_bf16(a, b1, acc1, 0, 0, 0);
    }
#pragma unroll
    for (int r = 0; r < 4; ++r) {
      const int ml = f * 16 + quad * 4 + r;
      if (ml < 49) {
        const size_t o = (size_t)n * 3136 + (size_t)ml * 64 + colg;
        x3b[o + lane16] = __float2bfloat16(fmaxf(acc0[r] + bb0, 0.f));
        x3b[o + 16 + lane16] = __float2bfloat16(fmaxf(acc1[r] + bb1, 0.f));
      }
    }
  }
}

// ---------------------------------------------------------------------------
// Unified bf16 MFMA NT-GEMM. Split-K factor = gridDim.z (partials to Cpart).
// ---------------------------------------------------------------------------
template<int BM, int MODE>
__global__ __launch_bounds__(256) void gemm_mfma(
    const __hip_bfloat16* __restrict__ Abase,
    const __hip_bfloat16* __restrict__ Wb,
    const float* __restrict__ bias1, const float* __restrict__ bias2,
    float* __restrict__ Cf, __hip_bfloat16* __restrict__ Cb,
    const int M, const int N, const int K, const int relu,
    float* __restrict__ Cpart) {
  constexpr int LDK = 40;
  __shared__ __align__(16) __hip_bfloat16 As[BM * LDK];
  __shared__ __align__(16) __hip_bfloat16 Ws[64 * LDK];
  const int tid = threadIdx.x;
  const int m0 = blockIdx.y * BM;
  const int n0 = blockIdx.x * 64;
  const int l = tid & 63;
  const int wv = tid >> 6;
  const int lane16 = l & 15;
  const int quad = l >> 4;
  constexpr int NF = (BM == 128) ? 4 : 2;
  const int m_base = (BM == 128) ? wv * 32 : (wv & 1) * 32;
  const int n_base = (BM == 128) ? 0 : (wv >> 1) * 32;
  constexpr int NCA = (BM == 128) ? 2 : 1;

  f32x4 acc[2][NF] = {};

  const __hip_bfloat16* arow[NCA];
  int acp[NCA];
#pragma unroll
  for (int c = 0; c < NCA; ++c) {
    const int id = tid + c * 256;
    const int row = id >> 2, cpos = id & 3;
    const int m = m0 + row;
    acp[c] = cpos;
    arow[c] = Abase + (size_t)m * K + cpos * 8;
  }
  const int wrow = tid >> 2, wcp = tid & 3;
  const __hip_bfloat16* wsrc = Wb + (size_t)(n0 + wrow) * K + wcp * 8;

  int s0 = 0, s1 = K >> 5;
  if (Cpart) {
    const int total = K >> 5;
    const int nz = gridDim.z;
    const int zz = blockIdx.z;
    const int q = total / nz, rr = total % nz;
    s0 = zz * q + (zz < rr ? zz : rr);
    s1 = s0 + q + (zz < rr ? 1 : 0);
  }
  for (int s = s0; s < s1; ++s) {
    uint4 av[NCA];
#pragma unroll
    for (int c = 0; c < NCA; ++c) {
      av[c] = *(const uint4*)(arow[c] + s * 32);
    }
    const uint4 wval = *(const uint4*)(wsrc + s * 32);
    __syncthreads();
#pragma unroll
    for (int c = 0; c < NCA; ++c) {
      const int row = (tid + c * 256) >> 2;
      *(uint4*)&As[row * LDK + acp[c] * 8] = av[c];
    }
    *(uint4*)&Ws[wrow * LDK + wcp * 8] = wval;
    __syncthreads();
    const bf16x8 a0 = *(const bf16x8*)&As[(m_base + lane16) * LDK + quad * 8];
    const bf16x8 a1 = *(const bf16x8*)&As[(m_base + 16 + lane16) * LDK + quad * 8];
#pragma unroll
    for (int nf = 0; nf < NF; ++nf) {
      const bf16x8 b = *(const bf16x8*)&Ws[(n_base + nf * 16 + lane16) * LDK + quad * 8];
      acc[0][nf] = __builtin_amdgcn_mfma_f32_16x16x32_bf16(a0, b, acc[0][nf], 0, 0, 0);
      acc[1][nf] = __builtin_amdgcn_mfma_f32_16x16x32_bf16(a1, b, acc[1][nf], 0, 0, 0);
    }
  }
  if (Cpart) {
    float* dst = Cpart + (size_t)blockIdx.z * M * N;
#pragma unroll
    for (int nf = 0; nf < NF; ++nf) {
      const int col = n0 + n_base + nf * 16 + lane16;
#pragma unroll
      for (int mf = 0; mf < 2; ++mf) {
#pragma unroll
        for (int r = 0; r < 4; ++r) {
          const int row = m0 + m_base + mf * 16 + quad * 4 + r;
          dst[(size_t)row * N + col] = acc[mf][nf][r];
        }
      }
    }
    return;
  }
#pragma unroll
  for (int nf = 0; nf < NF; ++nf) {
    const int col = n0 + n_base + nf * 16 + lane16;
    float bb = bias1[col];
    if (bias2) bb += bias2[col];
#pragma unroll
    for (int mf = 0; mf < 2; ++mf) {
#pragma unroll
      for (int r = 0; r < 4; ++r) {
        const int row = m0 + m_base + mf * 16 + quad * 4 + r;
        float v = acc[mf][nf][r] + bb;
        if (relu) v = fmaxf(v, 0.f);
        if (Cf) Cf[(size_t)row * N + col] = v;
        if (Cb) Cb[(size_t)row * N + col] = __float2bfloat16(v);
      }
    }
  }
}

// ---------------------------------------------------------------------------
// fc split-K(8) reduce + bias + relu + bf16 store, fused aux head.
// ---------------------------------------------------------------------------
__global__ __launch_bounds__(256) void fc_reduce(
    const float* __restrict__ part, const float* __restrict__ fcb,
    const float* __restrict__ aux_w, const float* __restrict__ aux_b,
    __hip_bfloat16* __restrict__ featb, float* __restrict__ outp) {
  const int row = blockIdx.x;
  const int tid = threadIdx.x;
  __shared__ float red[256];
  float auxacc = 0.f;
#pragma unroll
  for (int h = 0; h < 2; ++h) {
    const int c = tid + h * 256;
    const size_t base = (size_t)row * 512 + c;
    float v = 0.f;
#pragma unroll
    for (int j = 0; j < 8; ++j) v += part[(size_t)j * 1048576 + base];
    v += fcb[c];
    v = fmaxf(v, 0.f);
    featb[base] = __float2bfloat16(v);
    auxacc += v * aux_w[c];
  }
  red[tid] = auxacc;
  __syncthreads();
  for (int s = 128; s > 0; s >>= 1) {
    if (tid < s) red[tid] += red[tid + s];
    __syncthreads();
  }
  if (tid == 0) outp[6144 + row] = red[0] + aux_b[0];
}

// ---------------------------------------------------------------------------
// Grouped-segment MFMA LSTM (unchanged)
// ---------------------------------------------------------------------------
__global__ __launch_bounds__(1024, 4) void lstm_mfma(
    const float* __restrict__ gx, const __hip_bfloat16* __restrict__ whhb,
    const float* __restrict__ starts, const float* __restrict__ h0,
    const float* __restrict__ c0, const int* __restrict__ ord_b,
    const int* __restrict__ ord_t0, const int* __restrict__ ord_len,
    const int* __restrict__ nseg_p, float* __restrict__ hseq) {
  constexpr int LDH = 264;
  constexpr int PS  = 1028;
  __shared__ __align__(16) __hip_bfloat16 h_lds[16 * LDH];
  __shared__ __align__(16) float pre[16 * PS];
  __shared__ int sg_b[16], sg_t0[16], sg_len[16];
  const int g = blockIdx.x;
  const int nseg = *nseg_p;
  if (g * 16 >= nseg) return;
  const int tid = threadIdx.x;
  const int wv = tid >> 6;
  const int l = tid & 63;
  const int lane16 = l & 15, quad = l >> 4;
  if (tid < 16) {
    const int s = g * 16 + tid;
    sg_b[tid] = (s < nseg) ? ord_b[s] : 0;
    sg_t0[tid] = (s < nseg) ? ord_t0[s] : 0;
    sg_len[tid] = (s < nseg) ? ord_len[s] : 0;
  }
  __syncthreads();
  bf16x8 bfrag[2][8];
#pragma unroll
  for (int nt = 0; nt < 2; ++nt)
#pragma unroll
    for (int ks = 0; ks < 8; ++ks)
      bfrag[nt][ks] = *(const bf16x8*)&whhb[
          (size_t)(wv * 64 + nt * 16 + lane16) * 256 + ks * 32 + quad * 8];
  const __hip_bfloat16* bs2 = &whhb[(size_t)(wv * 64 + 32 + lane16) * 256 + quad * 8];
  const __hip_bfloat16* bs3 = &whhb[(size_t)(wv * 64 + 48 + lane16) * 256 + quad * 8];

  const int m_own = wv;
  const int u = l * 4;
  const int b_own = sg_b[m_own];
  const int t0_own = sg_t0[m_own];
  const int len_own = sg_len[m_own];
  float4 c_reg = make_float4(0.f, 0.f, 0.f, 0.f);
  {
    float4 hv = make_float4(0.f, 0.f, 0.f, 0.f);
    if (len_own > 0 && t0_own == 0) {
      const float keep = 1.0f - starts[b_own];
      const float4 h4 = *(const float4*)&h0[b_own * 256 + u];
      const float4 c4 = *(const float4*)&c0[b_own * 256 + u];
      hv = make_float4(h4.x * keep, h4.y * keep, h4.z * keep, h4.w * keep);
      c_reg = make_float4(c4.x * keep, c4.y * keep, c4.z * keep, c4.w * keep);
    }
    __hip_bfloat16* hd = &h_lds[m_own * LDH + u];
    hd[0] = __float2bfloat16(hv.x); hd[1] = __float2bfloat16(hv.y);
    hd[2] = __float2bfloat16(hv.z); hd[3] = __float2bfloat16(hv.w);
  }
  const int maxlen = sg_len[0];
  for (int tt = 0; tt < maxlen; ++tt) {
    __syncthreads();
    f32x4 acc[4] = {};
#pragma unroll
    for (int ks = 0; ks < 8; ++ks) {
      const bf16x8 b2 = *(const bf16x8*)(bs2 + ks * 32);
      const bf16x8 b3 = *(const bf16x8*)(bs3 + ks * 32);
      const bf16x8 a = *(const bf16x8*)&h_lds[lane16 * LDH + ks * 32 + quad * 8];
      acc[0] = __builtin_amdgcn_mfma_f32_16x16x32_bf16(a, bfrag[0][ks], acc[0], 0, 0, 0);
      acc[1] = __builtin_amdgcn_mfma_f32_16x16x32_bf16(a, bfrag[1][ks], acc[1], 0, 0, 0);
      acc[2] = __builtin_amdgcn_mfma_f32_16x16x32_bf16(a, b2, acc[2], 0, 0, 0);
      acc[3] = __builtin_amdgcn_mfma_f32_16x16x32_bf16(a, b3, acc[3], 0, 0, 0);
    }
#pragma unroll
    for (int nt = 0; nt < 4; ++nt)
#pragma unroll
      for (int r = 0; r < 4; ++r)
        pre[(quad * 4 + r) * PS + wv * 64 + nt * 16 + lane16] = acc[nt][r];
    __syncthreads();
    if (tt < len_own) {
      const int t = t0_own + tt;
      const size_t gbase = (size_t)(t * 16 + b_own) * 1024 + u;
      const float4 g0 = *(const float4*)&gx[gbase];
      const float4 g1 = *(const float4*)&gx[gbase + 256];
      const float4 g2 = *(const float4*)&gx[gbase + 512];
      const float4 g3 = *(const float4*)&gx[gbase + 768];
      const float4 p0 = *(const float4*)&pre[m_own * PS + u];
      const float4 p1 = *(const float4*)&pre[m_own * PS + u + 256];
      const float4 p2 = *(const float4*)&pre[m_own * PS + u + 512];
      const float4 p3 = *(const float4*)&pre[m_own * PS + u + 768];
      const float i0 = sigmoidf_(p0.x + g0.x), i1 = sigmoidf_(p0.y + g0.y),
                  i2 = sigmoidf_(p0.z + g0.z), i3 = sigmoidf_(p0.w + g0.w);
      const float f0 = sigmoidf_(p1.x + g1.x), f1 = sigmoidf_(p1.y + g1.y),
                  f2 = sigmoidf_(p1.z + g1.z), f3 = sigmoidf_(p1.w + g1.w);
      const float q0 = tanhf_(p2.x + g2.x), q1 = tanhf_(p2.y + g2.y),
                  q2 = tanhf_(p2.z + g2.z), q3 = tanhf_(p2.w + g2.w);
      const float o0 = sigmoidf_(p3.x + g3.x), o1 = sigmoidf_(p3.y + g3.y),
                  o2 = sigmoidf_(p3.z + g3.z), o3 = sigmoidf_(p3.w + g3.w);
      c_reg.x = fmaf(f0, c_reg.x, i0 * q0);
      c_reg.y = fmaf(f1, c_reg.y, i1 * q1);
      c_reg.z = fmaf(f2, c_reg.z, i2 * q2);
      c_reg.w = fmaf(f3, c_reg.w, i3 * q3);
      const float4 h4 = make_float4(o0 * tanhf_(c_reg.x), o1 * tanhf_(c_reg.y),
                                    o2 * tanhf_(c_reg.z), o3 * tanhf_(c_reg.w));
      __hip_bfloat16* hd = &h_lds[m_own * LDH + u];
      hd[0] = __float2bfloat16(h4.x); hd[1] = __float2bfloat16(h4.y);
      hd[2] = __float2bfloat16(h4.z); hd[3] = __float2bfloat16(h4.w);
      *(float4*)&hseq[(size_t)(t * 16 + b_own) * 256 + u] = h4;
    }
  }
}

// ---------------------------------------------------------------------------
// heads: wave-per-row (unchanged)
// ---------------------------------------------------------------------------
__global__ __launch_bounds__(256) void heads_kernel(
    const float* __restrict__ hseq, const int* __restrict__ actions,
    const float* __restrict__ actor_w, const float* __restrict__ actor_b,
    const float* __restrict__ critic_w, const float* __restrict__ critic_b,
    float* __restrict__ outp) {
  const int tid = threadIdx.x;
  const int wv = tid >> 6, l = tid & 63;
  const int tb = blockIdx.x * 4 + wv;
  const float4 h4 = *(const float4*)&hseq[(size_t)tb * 256 + l * 4];
  float part[19];
#pragma unroll
  for (int o = 0; o < 18; ++o) {
    const float4 w = *(const float4*)&actor_w[o * 256 + l * 4];
    part[o] = h4.x * w.x + h4.y * w.y + h4.z * w.z + h4.w * w.w;
  }
  {
    const float4 w = *(const float4*)&critic_w[l * 4];
    part[18] = h4.x * w.x + h4.y * w.y + h4.z * w.z + h4.w * w.w;
  }
#pragma unroll
  for (int off = 32; off > 0; off >>= 1) {
#pragma unroll
    for (int o = 0; o < 19; ++o) part[o] += __shfl_xor(part[o], off);
  }
  float lg[18];
  float m = -1e30f;
#pragma unroll
  for (int o = 0; o < 18; ++o) {
    lg[o] = part[o] + actor_b[o];
    m = fmaxf(m, lg[o]);
  }
  float se = 0.f;
#pragma unroll
  for (int o = 0; o < 18; ++o) se += __expf(lg[o] - m);
  const float lse = __logf(se);
  float ent = 0.f;
#pragma unroll
  for (int o = 0; o < 18; ++o) {
    const float lp = lg[o] - m - lse;
    ent -= __expf(lp) * lp;
  }
  if (l == 0) {
    const int a = actions[tb];
    outp[tb] = lg[a] - m - lse;
    outp[2048 + tb] = ent;
    outp[4096 + tb] = part[18] + critic_b[0];
  }
}

// ---------------------------------------------------------------------------
// launch
// ---------------------------------------------------------------------------
extern "C" void kernel_launch(void* const* d_in, const int* in_sizes, int n_in,
                              void* d_out, int out_size, void* d_ws, size_t ws_size,
                              hipStream_t stream) {
  const float* obs     = (const float*)d_in[0];
  const int*   actions = (const int*)d_in[1];
  const float* starts  = (const float*)d_in[2];
  const float* h0      = (const float*)d_in[3];
  const float* c0      = (const float*)d_in[4];
  const float* c1w     = (const float*)d_in[5];
  const float* c1b     = (const float*)d_in[6];
  const float* c2w     = (const float*)d_in[7];
  const float* c2b     = (const float*)d_in[8];
  const float* c3w     = (const float*)d_in[9];
  const float* c3b     = (const float*)d_in[10];
  const float* fcw     = (const float*)d_in[11];
  const float* fcb     = (const float*)d_in[12];
  const float* wih     = (const float*)d_in[13];
  const float* whh     = (const float*)d_in[14];
  const float* bih     = (const float*)d_in[15];
  const float* bhh     = (const float*)d_in[16];
  const float* aw      = (const float*)d_in[17];
  const float* ab      = (const float*)d_in[18];
  const float* cw      = (const float*)d_in[19];
  const float* cb      = (const float*)d_in[20];
  const float* auxw    = (const float*)d_in[21];
  const float* auxb    = (const float*)d_in[22];

  char* ws = (char*)d_ws;
  __hip_bfloat16* x1b   = (__hip_bfloat16*)(ws + OFF_X1B);
  __hip_bfloat16* x2b   = (__hip_bfloat16*)(ws + OFF_X2B);
  __hip_bfloat16* x3b   = (__hip_bfloat16*)(ws + OFF_X3B);
  __hip_bfloat16* featb = (__hip_bfloat16*)(ws + OFF_FEATB);
  __hip_bfloat16* w2b   = (__hip_bfloat16*)(ws + OFF_W2B);
  __hip_bfloat16* w3b   = (__hip_bfloat16*)(ws + OFF_W3B);
  __hip_bfloat16* fcwb  = (__hip_bfloat16*)(ws + OFF_FCWB);
  __hip_bfloat16* wihb  = (__hip_bfloat16*)(ws + OFF_WIHB);
  __hip_bfloat16* w1b   = (__hip_bfloat16*)(ws + OFF_W1B);
  __hip_bfloat16* whhb  = (__hip_bfloat16*)(ws + OFF_WHHB);
  float* gx   = (float*)(ws + OFF_GX);
  float* hseq = (float*)(ws + OFF_HSEQ);
  int* ord_b   = (int*)(ws + OFF_ORDB);
  int* ord_t0  = (int*)(ws + OFF_ORDT0);
  int* ord_len = (int*)(ws + OFF_ORDLEN);
  int* nseg    = (int*)(ws + OFF_NSEG);
  float* fcpart= (float*)(ws + OFF_FCPART);
  float* outp = (float*)d_out;

  prep_kernel<<<9649, 256, 0, stream>>>(c1w, c2w, c3w, fcw, wih, whh,
                                        w1b, w2b, w3b, fcwb, wihb, whhb,
                                        starts, ord_b, ord_t0, ord_len, nseg);
  conv1_dma<<<4096, 512, 0, stream>>>(obs, w1b, c1b, x1b);
  conv2_dma<<<4096, 512, 0, stream>>>(x1b, w2b, c2b, x2b);
  conv3_dma<<<4096, 256, 0, stream>>>(x2b, w3b, c3b, x3b);
  gemm_mfma<64, 0><<<dim3(8, 32, 8), 256, 0, stream>>>(
      x3b, fcwb, fcb, nullptr, nullptr, nullptr, 2048, 512, 3136, 0, fcpart);
  fc_reduce<<<2048, 256, 0, stream>>>(fcpart, fcb, auxw, auxb, featb, outp);
  gemm_mfma<64, 0><<<dim3(16, 32), 256, 0, stream>>>(
      featb, wihb, bih, bhh, gx, nullptr, 2048, 1024, 512, 0, nullptr);
  lstm_mfma<<<128, 1024, 0, stream>>>(gx, whhb, starts, h0, c0,
                                      ord_b, ord_t0, ord_len, nseg, hseq);
  heads_kernel<<<512, 256, 0, stream>>>(hseq, actions, aw, ab, cw, cb, outp);
}

// Round 15
// 644.769 us; speedup vs baseline: 1.0012x; 1.0012x over previous
//
#include <hip/hip_runtime.h>
#include <hip/hip_bf16.h>
#include <cstddef>

typedef __attribute__((ext_vector_type(8))) short bf16x8;
typedef __attribute__((ext_vector_type(4))) float f32x4;

// ---------------------------------------------------------------------------
// Workspace byte offsets (x1b/x2b padded layouts for DMA-friendly conv chain)
// ---------------------------------------------------------------------------
static constexpr size_t OFF_X1B   = 0;          // bf16 [2048][20][20][40] (pad 40)
static constexpr size_t OFF_X2B   = 65536000;   // bf16 [2048][9][9][72]  (pad 72)
static constexpr size_t OFF_X3B   = 89423872;   // bf16 [2048][3136] k=sp*64+ci
static constexpr size_t OFF_FEATB = 102268928;  // bf16 [2048][512]
static constexpr size_t OFF_W2B   = 104366080;  // bf16 [64][512]
static constexpr size_t OFF_W3B   = 104431616;  // bf16 [64][576]
static constexpr size_t OFF_FCWB  = 104505344;  // bf16 [512][3136]
static constexpr size_t OFF_WIHB  = 107716608;  // bf16 [1024][512]
static constexpr size_t OFF_GX    = 108765184;  // f32 [2048][1024]
static constexpr size_t OFF_HSEQ  = 117153792;  // f32 [2048][256]
static constexpr size_t OFF_W1B   = 119250944;  // bf16 [32][256]
static constexpr size_t OFF_WHHB  = 119267328;  // bf16 [1024][256]
static constexpr size_t OFF_ORDB  = 119791616;  // int[2048]
static constexpr size_t OFF_ORDT0 = 119799808;  // int[2048]
static constexpr size_t OFF_ORDLEN= 119808000;  // int[2048]
static constexpr size_t OFF_NSEG  = 119816192;  // int[1]
static constexpr size_t OFF_FCPART= 119824384;  // f32 [8][2048][512]

__device__ __forceinline__ float sigmoidf_(float x) {
  return 1.0f / (1.0f + __expf(-x));
}
__device__ __forceinline__ float tanhf_(float x) {
  return 1.0f - 2.0f / (__expf(2.0f * x) + 1.0f);
}
__device__ __forceinline__ short f2bfs(float x) {
  union { __hip_bfloat16 b; short s; } cv;
  cv.b = __float2bfloat16(x);
  return cv.s;
}
// async global->LDS DMA, 16B per lane. LDS dest = wave-uniform base + lane*16;
// global src is per-lane. Drained by the vmcnt(0) the compiler emits before
// s_barrier (__syncthreads).
__device__ __forceinline__ void dma16(const void* g, void* l) {
  __builtin_amdgcn_global_load_lds(
      (const __attribute__((address_space(1))) unsigned int*)g,
      (__attribute__((address_space(3))) unsigned int*)l, 16, 0, 0);
}

// ---------------------------------------------------------------------------
// Prep + plan merged: blocks 0..9647 do weight convert/reorder; block 9648
// does the segment planning (saves one launch + dependency edge).
// ---------------------------------------------------------------------------
__global__ __launch_bounds__(256) void prep_kernel(
    const float* __restrict__ c1w, const float* __restrict__ c2w,
    const float* __restrict__ c3w, const float* __restrict__ fcw,
    const float* __restrict__ wih, const float* __restrict__ whh,
    __hip_bfloat16* __restrict__ w1b,
    __hip_bfloat16* __restrict__ w2b, __hip_bfloat16* __restrict__ w3b,
    __hip_bfloat16* __restrict__ fcwb, __hip_bfloat16* __restrict__ wihb,
    __hip_bfloat16* __restrict__ whhb,
    const float* __restrict__ starts, int* __restrict__ ord_b,
    int* __restrict__ ord_t0, int* __restrict__ ord_len,
    int* __restrict__ nseg_out) {
  const int tid = threadIdx.x;
  if (blockIdx.x == 9648) {
    // ---- plan body ----
    __shared__ float s_starts[2048];
    __shared__ int s_t0[2048];
    __shared__ int s_len[2048];
    __shared__ int cnt[16];
    __shared__ int hist[132];
    __shared__ int off[132];
    {
      float4* d = (float4*)s_starts;
      const float4* s = (const float4*)starts;
#pragma unroll
      for (int i = 0; i < 2; ++i) d[tid + i * 256] = s[tid + i * 256];
    }
    if (tid < 132) hist[tid] = 0;
    __syncthreads();
    if (tid < 16) {
      int b = tid, c = 0;
      for (int t = 0; t < 128; ++t) {
        float s = s_starts[t * 16 + b];
        if (t == 0 || s != 0.0f) {
          if (c > 0) s_len[b * 128 + c - 1] = t - s_t0[b * 128 + c - 1];
          s_t0[b * 128 + c] = t;
          ++c;
        }
      }
      s_len[b * 128 + c - 1] = 128 - s_t0[b * 128 + c - 1];
      cnt[b] = c;
    }
    __syncthreads();
    for (int idx = tid; idx < 2048; idx += 256) {
      int b = idx >> 7, i = idx & 127;
      if (i < cnt[b]) atomicAdd(&hist[s_len[idx]], 1);
    }
    __syncthreads();
    if (tid == 0) {
      int running = 0;
      for (int L = 128; L >= 1; --L) { off[L] = running; running += hist[L]; }
      *nseg_out = running;
    }
    __syncthreads();
    for (int idx = tid; idx < 2048; idx += 256) {
      int b = idx >> 7, i = idx & 127;
      if (i < cnt[b]) {
        int len = s_len[idx];
        int pos = atomicAdd(&off[len], 1);
        ord_b[pos] = b;
        ord_t0[pos] = s_t0[idx];
        ord_len[pos] = len;
      }
    }
    return;
  }
  int i = blockIdx.x * 256 + tid;
  if (i < 32768) {                          // w2b: k=(ky*4+kx)*32+ci
    int o = i >> 9, k = i & 511;
    int pos = k >> 5, ci = k & 31;
    int ky = pos >> 2, kx = pos & 3;
    w2b[i] = __float2bfloat16(c2w[o * 512 + ci * 16 + ky * 4 + kx]);
  } else if (i < 69632) {                   // w3b: k=(ky*3+kx)*64+ci
    int j = i - 32768;
    int o = j / 576, k = j - o * 576;
    int pos = k >> 6, ci = k & 63;
    int ky = pos / 3, kx = pos - ky * 3;
    w3b[j] = __float2bfloat16(c3w[o * 576 + ci * 9 + ky * 3 + kx]);
  } else if (i < 1675264) {                 // fcwb: k=sp*64+ci
    int j = i - 69632;
    int o = j / 3136, k = j - o * 3136;
    int sp = k >> 6, ci = k & 63;
    fcwb[j] = __float2bfloat16(fcw[o * 3136 + ci * 49 + sp]);
  } else if (i < 2199552) {                 // wihb: native
    int j = i - 1675264;
    wihb[j] = __float2bfloat16(wih[j]);
  } else if (i < 2461696) {                 // whhb: straight copy [1024][256]
    int j = i - 2199552;
    whhb[j] = __float2bfloat16(whh[j]);
  } else if (i < 2469888) {                 // w1b: k=ky*32+ci*8+kx, *(1/255)
    int j = i - 2461696;
    int oc = j >> 8, k = j & 255;
    int ky = k >> 5, rem = k & 31;
    int ci = rem >> 3, kx = rem & 7;
    w1b[j] = __float2bfloat16(c1w[oc * 256 + ci * 64 + ky * 8 + kx] * (1.0f / 255.0f));
  }
}

// ---------------------------------------------------------------------------
// conv1 v6: 512 threads (8 waves). DMA split 8 ways (2 waves per channel
// region); frag loop f += 8 (max 2 frags/wave). LDS -> 2 blocks/CU.
// Output: padded CL [20][20][40].
// ---------------------------------------------------------------------------
__global__ __launch_bounds__(512, 4) void conv1_dma(
    const float* __restrict__ obs, const __hip_bfloat16* __restrict__ w1b,
    const float* __restrict__ bias1, __hip_bfloat16* __restrict__ x1b) {
  constexpr int LDW = 264;
  __shared__ __align__(16) float imgf[15552];          // 4 regions x 3840 + pad
  __shared__ __align__(16) __hip_bfloat16 Ws[32 * LDW];
  const int tid = threadIdx.x;
  const int wv = tid >> 6, l = tid & 63;
  const int lane16 = l & 15, quad = l >> 4;
  const int n = blockIdx.x >> 1, h = blockIdx.x & 1;

  for (int i = tid; i < 1024; i += 512) {
    const int r = i >> 5, c = (i & 31) * 8;
    *(uint4*)&Ws[r * LDW + c] = *(const uint4*)&w1b[r * 256 + c];
  }
  {
    // waves (2c, 2c+1) stage channel region c: 44 rows x 84 f32 = 14784 B
    const int reg = wv >> 1, half = wv & 1;
    const char* gbase = (const char*)(obs + (size_t)n * 28224 + reg * 7056 + h * 3360);
    char* lbase = (char*)imgf + reg * 15360;
    const int k0 = half ? 8 : 0, k1 = half ? 15 : 8;
    for (int k = k0; k < k1; ++k) {
      int off = k * 1024 + l * 16;
      if (off >= 14784) off = 0;     // tail lanes: clamp src, dest lands in pad
      dma16(gbase + off, lbase + k * 1024);
    }
  }
  __syncthreads();   // compiler drains vmcnt(0): DMA complete

  const float bb0 = bias1[lane16];
  const float bb1 = bias1[16 + lane16];
  for (int f = wv; f < 13; f += 8) {
    const int sp = f * 16 + lane16;              // 0..207 (valid < 200)
    const int oy = sp / 20, ox = sp - oy * 20;
    const float* ab = &imgf[quad * 3840 + (oy * 4) * 84 + ox * 4];
    f32x4 acc0 = {}, acc1 = {};
#pragma unroll
    for (int s = 0; s < 8; ++s) {
      const f32x4 lo = *(const f32x4*)(ab + s * 84);
      const f32x4 hi = *(const f32x4*)(ab + s * 84 + 4);
      bf16x8 a;
      a[0] = f2bfs(lo[0]); a[1] = f2bfs(lo[1]); a[2] = f2bfs(lo[2]); a[3] = f2bfs(lo[3]);
      a[4] = f2bfs(hi[0]); a[5] = f2bfs(hi[1]); a[6] = f2bfs(hi[2]); a[7] = f2bfs(hi[3]);
      const bf16x8 b0 = *(const bf16x8*)&Ws[lane16 * LDW + s * 32 + quad * 8];
      const bf16x8 b1 = *(const bf16x8*)&Ws[(16 + lane16) * LDW + s * 32 + quad * 8];
      acc0 = __builtin_amdgcn_mfma_f32_16x16x32_bf16(a, b0, acc0, 0, 0, 0);
      acc1 = __builtin_amdgcn_mfma_f32_16x16x32_bf16(a, b1, acc1, 0, 0, 0);
    }
    const size_t base = (size_t)n * 16000 + (size_t)(h * 200) * 40;
#pragma unroll
    for (int r = 0; r < 4; ++r) {
      const int ml = f * 16 + quad * 4 + r;
      if (ml < 200) {
        x1b[base + ml * 40 + lane16] = __float2bfloat16(fmaxf(acc0[r] + bb0, 0.f));
        x1b[base + ml * 40 + 16 + lane16] = __float2bfloat16(fmaxf(acc1[r] + bb1, 0.f));
      }
    }
  }
}

// ---------------------------------------------------------------------------
// conv2 v6: 512 threads (8 waves). DMA split 8 ways (4 chunks/wave);
// 6 frags over 8 waves -> max 1 frag/wave. LDS -> 2/CU.
// ---------------------------------------------------------------------------
__global__ __launch_bounds__(512, 4) void conv2_dma(
    const __hip_bfloat16* __restrict__ x1b, const __hip_bfloat16* __restrict__ w2b,
    const float* __restrict__ bias, __hip_bfloat16* __restrict__ x2b) {
  constexpr int LDW = 520;
  __shared__ __align__(16) __hip_bfloat16 img[24 * 800];   // [24][20][40]
  __shared__ __align__(16) __hip_bfloat16 Ws[32 * LDW];
  const int tid = threadIdx.x;
  const int wv = tid >> 6, l = tid & 63;
  const int lane16 = l & 15, quad = l >> 4;
  const int n = blockIdx.x >> 1, nh = blockIdx.x & 1;

  for (int i = tid; i < 2048; i += 512) {
    const int r = i >> 6, c = (i & 63) * 8;
    *(uint4*)&Ws[r * LDW + c] = *(const uint4*)&w2b[(nh * 32 + r) * 512 + c];
  }
  {
    const char* g = (const char*)(x1b + (size_t)n * 16000);
    char* lb = (char*)img;
    for (int i = 0; i < 4; ++i) {
      const int k = wv * 4 + i;
      int off = k * 1024 + l * 16;
      if (off >= 32000) off = 0;
      dma16(g + off, lb + k * 1024);
    }
  }
  __syncthreads();

  const int colg = nh * 32;
  const float bb0 = bias[colg + lane16];
  const float bb1 = bias[colg + 16 + lane16];
  for (int f = wv; f < 6; f += 8) {
    const int sp = f * 16 + lane16;              // 0..95 (valid < 81)
    const int oy = sp / 9, ox = sp - oy * 9;
    const __hip_bfloat16* ab = &img[((oy * 2) * 20 + ox * 2) * 40 + quad * 8];
    f32x4 acc0 = {}, acc1 = {};
#pragma unroll
    for (int s = 0; s < 16; ++s) {
      const int ky = s >> 2, kx = s & 3;
      const bf16x8 a = *(const bf16x8*)(ab + (ky * 20 + kx) * 40);
      const bf16x8 b0 = *(const bf16x8*)&Ws[lane16 * LDW + s * 32 + quad * 8];
      const bf16x8 b1 = *(const bf16x8*)&Ws[(16 + lane16) * LDW + s * 32 + quad * 8];
      acc0 = __builtin_amdgcn_mfma_f32_16x16x32_bf16(a, b0, acc0, 0, 0, 0);
      acc1 = __builtin_amdgcn_mfma_f32_16x16x32_bf16(a, b1, acc1, 0, 0, 0);
    }
#pragma unroll
    for (int r = 0; r < 4; ++r) {
      const int ml = f * 16 + quad * 4 + r;
      if (ml < 81) {
        const size_t o = (size_t)n * 5832 + (size_t)ml * 72 + colg;
        x2b[o + lane16] = __float2bfloat16(fmaxf(acc0[r] + bb0, 0.f));
        x2b[o + 16 + lane16] = __float2bfloat16(fmaxf(acc1[r] + bb1, 0.f));
      }
    }
  }
}

// ---------------------------------------------------------------------------
// conv3 v5: per-image x col-half blocks, 3 blocks/CU.
// ---------------------------------------------------------------------------
__global__ __launch_bounds__(256, 3) void conv3_dma(
    const __hip_bfloat16* __restrict__ x2b, const __hip_bfloat16* __restrict__ w3b,
    const float* __restrict__ bias, __hip_bfloat16* __restrict__ x3b) {
  constexpr int LDW = 584;
  __shared__ __align__(16) __hip_bfloat16 img[12 * 648];   // [12][9][72]
  __shared__ __align__(16) __hip_bfloat16 Ws[32 * LDW];
  const int tid = threadIdx.x;
  const int wv = tid >> 6, l = tid & 63;
  const int lane16 = l & 15, quad = l >> 4;
  const int n = blockIdx.x >> 1, nh = blockIdx.x & 1;

  for (int i = tid; i < 2304; i += 256) {
    const int r = i / 72, c = (i - r * 72) * 8;
    *(uint4*)&Ws[r * LDW + c] = *(const uint4*)&w3b[(nh * 32 + r) * 576 + c];
  }
  {
    const char* g = (const char*)(x2b + (size_t)n * 5832);
    char* lb = (char*)img;
    for (int i = 0; i < 3; ++i) {
      const int k = wv * 3 + i;
      int off = k * 1024 + l * 16;
      if (off >= 11664) off = 0;
      dma16(g + off, lb + k * 1024);
    }
  }
  __syncthreads();

  const int colg = nh * 32;
  const float bb0 = bias[colg + lane16];
  const float bb1 = bias[colg + 16 + lane16];
  {
    const int f = wv;                            // exactly 1 frag per wave
    const int sp = f * 16 + lane16;              // 0..63 (valid < 49)
    const int oy = sp / 7, ox = sp - oy * 7;
    const __hip_bfloat16* ab = &img[(oy * 9 + ox) * 72 + quad * 8];
    f32x4 acc0 = {}, acc1 = {};
#pragma unroll
    for (int s = 0; s < 18; ++s) {
      const int pos = s >> 1, half = s & 1;
      const int ky = pos / 3, kx = pos - ky * 3;
      const bf16x8 a = *(const bf16x8*)(ab + (ky * 9 + kx) * 72 + half * 32);
      const bf16x8 b0 = *(const bf16x8*)&Ws[lane16 * LDW + s * 32 + quad * 8];
      const bf16x8 b1 = *(const bf16x8*)&Ws[(16 + lane16) * LDW + s * 32 + quad * 8];
      acc0 = __builtin_amdgcn_mfma_f32_16x16x32_bf16(a, b0, acc0, 0, 0, 0);
      acc1 = __builtin_amdgcn_mfma_f32_16x16x32_bf16(a, b1, acc1, 0, 0, 0);
    }
#pragma unroll
    for (int r = 0; r < 4; ++r) {
      const int ml = f * 16 + quad * 4 + r;
      if (ml < 49) {
        const size_t o = (size_t)n * 3136 + (size_t)ml * 64 + colg;
        x3b[o + lane16] = __float2bfloat16(fmaxf(acc0[r] + bb0, 0.f));
        x3b[o + 16 + lane16] = __float2bfloat16(fmaxf(acc1[r] + bb1, 0.f));
      }
    }
  }
}

// ---------------------------------------------------------------------------
// Unified bf16 MFMA NT-GEMM. Split-K factor = gridDim.z (partials to Cpart).
// ---------------------------------------------------------------------------
template<int BM, int MODE>
__global__ __launch_bounds__(256) void gemm_mfma(
    const __hip_bfloat16* __restrict__ Abase,
    const __hip_bfloat16* __restrict__ Wb,
    const float* __restrict__ bias1, const float* __restrict__ bias2,
    float* __restrict__ Cf, __hip_bfloat16* __restrict__ Cb,
    const int M, const int N, const int K, const int relu,
    float* __restrict__ Cpart) {
  constexpr int LDK = 40;
  __shared__ __align__(16) __hip_bfloat16 As[BM * LDK];
  __shared__ __align__(16) __hip_bfloat16 Ws[64 * LDK];
  const int tid = threadIdx.x;
  const int m0 = blockIdx.y * BM;
  const int n0 = blockIdx.x * 64;
  const int l = tid & 63;
  const int wv = tid >> 6;
  const int lane16 = l & 15;
  const int quad = l >> 4;
  constexpr int NF = (BM == 128) ? 4 : 2;
  const int m_base = (BM == 128) ? wv * 32 : (wv & 1) * 32;
  const int n_base = (BM == 128) ? 0 : (wv >> 1) * 32;
  constexpr int NCA = (BM == 128) ? 2 : 1;

  f32x4 acc[2][NF] = {};

  const __hip_bfloat16* arow[NCA];
  int acp[NCA];
#pragma unroll
  for (int c = 0; c < NCA; ++c) {
    const int id = tid + c * 256;
    const int row = id >> 2, cpos = id & 3;
    const int m = m0 + row;
    acp[c] = cpos;
    arow[c] = Abase + (size_t)m * K + cpos * 8;
  }
  const int wrow = tid >> 2, wcp = tid & 3;
  const __hip_bfloat16* wsrc = Wb + (size_t)(n0 + wrow) * K + wcp * 8;

  int s0 = 0, s1 = K >> 5;
  if (Cpart) {
    const int total = K >> 5;
    const int nz = gridDim.z;
    const int zz = blockIdx.z;
    const int q = total / nz, rr = total % nz;
    s0 = zz * q + (zz < rr ? zz : rr);
    s1 = s0 + q + (zz < rr ? 1 : 0);
  }
  for (int s = s0; s < s1; ++s) {
    uint4 av[NCA];
#pragma unroll
    for (int c = 0; c < NCA; ++c) {
      av[c] = *(const uint4*)(arow[c] + s * 32);
    }
    const uint4 wval = *(const uint4*)(wsrc + s * 32);
    __syncthreads();
#pragma unroll
    for (int c = 0; c < NCA; ++c) {
      const int row = (tid + c * 256) >> 2;
      *(uint4*)&As[row * LDK + acp[c] * 8] = av[c];
    }
    *(uint4*)&Ws[wrow * LDK + wcp * 8] = wval;
    __syncthreads();
    const bf16x8 a0 = *(const bf16x8*)&As[(m_base + lane16) * LDK + quad * 8];
    const bf16x8 a1 = *(const bf16x8*)&As[(m_base + 16 + lane16) * LDK + quad * 8];
#pragma unroll
    for (int nf = 0; nf < NF; ++nf) {
      const bf16x8 b = *(const bf16x8*)&Ws[(n_base + nf * 16 + lane16) * LDK + quad * 8];
      acc[0][nf] = __builtin_amdgcn_mfma_f32_16x16x32_bf16(a0, b, acc[0][nf], 0, 0, 0);
      acc[1][nf] = __builtin_amdgcn_mfma_f32_16x16x32_bf16(a1, b, acc[1][nf], 0, 0, 0);
    }
  }
  if (Cpart) {
    float* dst = Cpart + (size_t)blockIdx.z * M * N;
#pragma unroll
    for (int nf = 0; nf < NF; ++nf) {
      const int col = n0 + n_base + nf * 16 + lane16;
#pragma unroll
      for (int mf = 0; mf < 2; ++mf) {
#pragma unroll
        for (int r = 0; r < 4; ++r) {
          const int row = m0 + m_base + mf * 16 + quad * 4 + r;
          dst[(size_t)row * N + col] = acc[mf][nf][r];
        }
      }
    }
    return;
  }
#pragma unroll
  for (int nf = 0; nf < NF; ++nf) {
    const int col = n0 + n_base + nf * 16 + lane16;
    float bb = bias1[col];
    if (bias2) bb += bias2[col];
#pragma unroll
    for (int mf = 0; mf < 2; ++mf) {
#pragma unroll
      for (int r = 0; r < 4; ++r) {
        const int row = m0 + m_base + mf * 16 + quad * 4 + r;
        float v = acc[mf][nf][r] + bb;
        if (relu) v = fmaxf(v, 0.f);
        if (Cf) Cf[(size_t)row * N + col] = v;
        if (Cb) Cb[(size_t)row * N + col] = __float2bfloat16(v);
      }
    }
  }
}

// ---------------------------------------------------------------------------
// fc split-K(8) reduce + bias + relu + bf16 store, fused aux head.
// ---------------------------------------------------------------------------
__global__ __launch_bounds__(256) void fc_reduce(
    const float* __restrict__ part, const float* __restrict__ fcb,
    const float* __restrict__ aux_w, const float* __restrict__ aux_b,
    __hip_bfloat16* __restrict__ featb, float* __restrict__ outp) {
  const int row = blockIdx.x;
  const int tid = threadIdx.x;
  __shared__ float red[256];
  float auxacc = 0.f;
#pragma unroll
  for (int h = 0; h < 2; ++h) {
    const int c = tid + h * 256;
    const size_t base = (size_t)row * 512 + c;
    float v = 0.f;
#pragma unroll
    for (int j = 0; j < 8; ++j) v += part[(size_t)j * 1048576 + base];
    v += fcb[c];
    v = fmaxf(v, 0.f);
    featb[base] = __float2bfloat16(v);
    auxacc += v * aux_w[c];
  }
  red[tid] = auxacc;
  __syncthreads();
  for (int s = 128; s > 0; s >>= 1) {
    if (tid < s) red[tid] += red[tid + s];
    __syncthreads();
  }
  if (tid == 0) outp[6144 + row] = red[0] + aux_b[0];
}

// ---------------------------------------------------------------------------
// Grouped-segment MFMA LSTM (unchanged)
// ---------------------------------------------------------------------------
__global__ __launch_bounds__(1024, 4) void lstm_mfma(
    const float* __restrict__ gx, const __hip_bfloat16* __restrict__ whhb,
    const float* __restrict__ starts, const float* __restrict__ h0,
    const float* __restrict__ c0, const int* __restrict__ ord_b,
    const int* __restrict__ ord_t0, const int* __restrict__ ord_len,
    const int* __restrict__ nseg_p, float* __restrict__ hseq) {
  constexpr int LDH = 264;
  constexpr int PS  = 1028;
  __shared__ __align__(16) __hip_bfloat16 h_lds[16 * LDH];
  __shared__ __align__(16) float pre[16 * PS];
  __shared__ int sg_b[16], sg_t0[16], sg_len[16];
  const int g = blockIdx.x;
  const int nseg = *nseg_p;
  if (g * 16 >= nseg) return;
  const int tid = threadIdx.x;
  const int wv = tid >> 6;
  const int l = tid & 63;
  const int lane16 = l & 15, quad = l >> 4;
  if (tid < 16) {
    const int s = g * 16 + tid;
    sg_b[tid] = (s < nseg) ? ord_b[s] : 0;
    sg_t0[tid] = (s < nseg) ? ord_t0[s] : 0;
    sg_len[tid] = (s < nseg) ? ord_len[s] : 0;
  }
  __syncthreads();
  bf16x8 bfrag[2][8];
#pragma unroll
  for (int nt = 0; nt < 2; ++nt)
#pragma unroll
    for (int ks = 0; ks < 8; ++ks)
      bfrag[nt][ks] = *(const bf16x8*)&whhb[
          (size_t)(wv * 64 + nt * 16 + lane16) * 256 + ks * 32 + quad * 8];
  const __hip_bfloat16* bs2 = &whhb[(size_t)(wv * 64 + 32 + lane16) * 256 + quad * 8];
  const __hip_bfloat16* bs3 = &whhb[(size_t)(wv * 64 + 48 + lane16) * 256 + quad * 8];

  const int m_own = wv;
  const int u = l * 4;
  const int b_own = sg_b[m_own];
  const int t0_own = sg_t0[m_own];
  const int len_own = sg_len[m_own];
  float4 c_reg = make_float4(0.f, 0.f, 0.f, 0.f);
  {
    float4 hv = make_float4(0.f, 0.f, 0.f, 0.f);
    if (len_own > 0 && t0_own == 0) {
      const float keep = 1.0f - starts[b_own];
      const float4 h4 = *(const float4*)&h0[b_own * 256 + u];
      const float4 c4 = *(const float4*)&c0[b_own * 256 + u];
      hv = make_float4(h4.x * keep, h4.y * keep, h4.z * keep, h4.w * keep);
      c_reg = make_float4(c4.x * keep, c4.y * keep, c4.z * keep, c4.w * keep);
    }
    __hip_bfloat16* hd = &h_lds[m_own * LDH + u];
    hd[0] = __float2bfloat16(hv.x); hd[1] = __float2bfloat16(hv.y);
    hd[2] = __float2bfloat16(hv.z); hd[3] = __float2bfloat16(hv.w);
  }
  const int maxlen = sg_len[0];
  for (int tt = 0; tt < maxlen; ++tt) {
    __syncthreads();
    f32x4 acc[4] = {};
#pragma unroll
    for (int ks = 0; ks < 8; ++ks) {
      const bf16x8 b2 = *(const bf16x8*)(bs2 + ks * 32);
      const bf16x8 b3 = *(const bf16x8*)(bs3 + ks * 32);
      const bf16x8 a = *(const bf16x8*)&h_lds[lane16 * LDH + ks * 32 + quad * 8];
      acc[0] = __builtin_amdgcn_mfma_f32_16x16x32_bf16(a, bfrag[0][ks], acc[0], 0, 0, 0);
      acc[1] = __builtin_amdgcn_mfma_f32_16x16x32_bf16(a, bfrag[1][ks], acc[1], 0, 0, 0);
      acc[2] = __builtin_amdgcn_mfma_f32_16x16x32_bf16(a, b2, acc[2], 0, 0, 0);
      acc[3] = __builtin_amdgcn_mfma_f32_16x16x32_bf16(a, b3, acc[3], 0, 0, 0);
    }
#pragma unroll
    for (int nt = 0; nt < 4; ++nt)
#pragma unroll
      for (int r = 0; r < 4; ++r)
        pre[(quad * 4 + r) * PS + wv * 64 + nt * 16 + lane16] = acc[nt][r];
    __syncthreads();
    if (tt < len_own) {
      const int t = t0_own + tt;
      const size_t gbase = (size_t)(t * 16 + b_own) * 1024 + u;
      const float4 g0 = *(const float4*)&gx[gbase];
      const float4 g1 = *(const float4*)&gx[gbase + 256];
      const float4 g2 = *(const float4*)&gx[gbase + 512];
      const float4 g3 = *(const float4*)&gx[gbase + 768];
      const float4 p0 = *(const float4*)&pre[m_own * PS + u];
      const float4 p1 = *(const float4*)&pre[m_own * PS + u + 256];
      const float4 p2 = *(const float4*)&pre[m_own * PS + u + 512];
      const float4 p3 = *(const float4*)&pre[m_own * PS + u + 768];
      const float i0 = sigmoidf_(p0.x + g0.x), i1 = sigmoidf_(p0.y + g0.y),
                  i2 = sigmoidf_(p0.z + g0.z), i3 = sigmoidf_(p0.w + g0.w);
      const float f0 = sigmoidf_(p1.x + g1.x), f1 = sigmoidf_(p1.y + g1.y),
                  f2 = sigmoidf_(p1.z + g1.z), f3 = sigmoidf_(p1.w + g1.w);
      const float q0 = tanhf_(p2.x + g2.x), q1 = tanhf_(p2.y + g2.y),
                  q2 = tanhf_(p2.z + g2.z), q3 = tanhf_(p2.w + g2.w);
      const float o0 = sigmoidf_(p3.x + g3.x), o1 = sigmoidf_(p3.y + g3.y),
                  o2 = sigmoidf_(p3.z + g3.z), o3 = sigmoidf_(p3.w + g3.w);
      c_reg.x = fmaf(f0, c_reg.x, i0 * q0);
      c_reg.y = fmaf(f1, c_reg.y, i1 * q1);
      c_reg.z = fmaf(f2, c_reg.z, i2 * q2);
      c_reg.w = fmaf(f3, c_reg.w, i3 * q3);
      const float4 h4 = make_float4(o0 * tanhf_(c_reg.x), o1 * tanhf_(c_reg.y),
                                    o2 * tanhf_(c_reg.z), o3 * tanhf_(c_reg.w));
      __hip_bfloat16* hd = &h_lds[m_own * LDH + u];
      hd[0] = __float2bfloat16(h4.x); hd[1] = __float2bfloat16(h4.y);
      hd[2] = __float2bfloat16(h4.z); hd[3] = __float2bfloat16(h4.w);
      *(float4*)&hseq[(size_t)(t * 16 + b_own) * 256 + u] = h4;
    }
  }
}

// ---------------------------------------------------------------------------
// heads: wave-per-row (unchanged)
// ---------------------------------------------------------------------------
__global__ __launch_bounds__(256) void heads_kernel(
    const float* __restrict__ hseq, const int* __restrict__ actions,
    const float* __restrict__ actor_w, const float* __restrict__ actor_b,
    const float* __restrict__ critic_w, const float* __restrict__ critic_b,
    float* __restrict__ outp) {
  const int tid = threadIdx.x;
  const int wv = tid >> 6, l = tid & 63;
  const int tb = blockIdx.x * 4 + wv;
  const float4 h4 = *(const float4*)&hseq[(size_t)tb * 256 + l * 4];
  float part[19];
#pragma unroll
  for (int o = 0; o < 18; ++o) {
    const float4 w = *(const float4*)&actor_w[o * 256 + l * 4];
    part[o] = h4.x * w.x + h4.y * w.y + h4.z * w.z + h4.w * w.w;
  }
  {
    const float4 w = *(const float4*)&critic_w[l * 4];
    part[18] = h4.x * w.x + h4.y * w.y + h4.z * w.z + h4.w * w.w;
  }
#pragma unroll
  for (int off = 32; off > 0; off >>= 1) {
#pragma unroll
    for (int o = 0; o < 19; ++o) part[o] += __shfl_xor(part[o], off);
  }
  float lg[18];
  float m = -1e30f;
#pragma unroll
  for (int o = 0; o < 18; ++o) {
    lg[o] = part[o] + actor_b[o];
    m = fmaxf(m, lg[o]);
  }
  float se = 0.f;
#pragma unroll
  for (int o = 0; o < 18; ++o) se += __expf(lg[o] - m);
  const float lse = __logf(se);
  float ent = 0.f;
#pragma unroll
  for (int o = 0; o < 18; ++o) {
    const float lp = lg[o] - m - lse;
    ent -= __expf(lp) * lp;
  }
  if (l == 0) {
    const int a = actions[tb];
    outp[tb] = lg[a] - m - lse;
    outp[2048 + tb] = ent;
    outp[4096 + tb] = part[18] + critic_b[0];
  }
}

// ---------------------------------------------------------------------------
// launch
// ---------------------------------------------------------------------------
extern "C" void kernel_launch(void* const* d_in, const int* in_sizes, int n_in,
                              void* d_out, int out_size, void* d_ws, size_t ws_size,
                              hipStream_t stream) {
  const float* obs     = (const float*)d_in[0];
  const int*   actions = (const int*)d_in[1];
  const float* starts  = (const float*)d_in[2];
  const float* h0      = (const float*)d_in[3];
  const float* c0      = (const float*)d_in[4];
  const float* c1w     = (const float*)d_in[5];
  const float* c1b     = (const float*)d_in[6];
  const float* c2w     = (const float*)d_in[7];
  const float* c2b     = (const float*)d_in[8];
  const float* c3w     = (const float*)d_in[9];
  const float* c3b     = (const float*)d_in[10];
  const float* fcw     = (const float*)d_in[11];
  const float* fcb     = (const float*)d_in[12];
  const float* wih     = (const float*)d_in[13];
  const float* whh     = (const float*)d_in[14];
  const float* bih     = (const float*)d_in[15];
  const float* bhh     = (const float*)d_in[16];
  const float* aw      = (const float*)d_in[17];
  const float* ab      = (const float*)d_in[18];
  const float* cw      = (const float*)d_in[19];
  const float* cb      = (const float*)d_in[20];
  const float* auxw    = (const float*)d_in[21];
  const float* auxb    = (const float*)d_in[22];

  char* ws = (char*)d_ws;
  __hip_bfloat16* x1b   = (__hip_bfloat16*)(ws + OFF_X1B);
  __hip_bfloat16* x2b   = (__hip_bfloat16*)(ws + OFF_X2B);
  __hip_bfloat16* x3b   = (__hip_bfloat16*)(ws + OFF_X3B);
  __hip_bfloat16* featb = (__hip_bfloat16*)(ws + OFF_FEATB);
  __hip_bfloat16* w2b   = (__hip_bfloat16*)(ws + OFF_W2B);
  __hip_bfloat16* w3b   = (__hip_bfloat16*)(ws + OFF_W3B);
  __hip_bfloat16* fcwb  = (__hip_bfloat16*)(ws + OFF_FCWB);
  __hip_bfloat16* wihb  = (__hip_bfloat16*)(ws + OFF_WIHB);
  __hip_bfloat16* w1b   = (__hip_bfloat16*)(ws + OFF_W1B);
  __hip_bfloat16* whhb  = (__hip_bfloat16*)(ws + OFF_WHHB);
  float* gx   = (float*)(ws + OFF_GX);
  float* hseq = (float*)(ws + OFF_HSEQ);
  int* ord_b   = (int*)(ws + OFF_ORDB);
  int* ord_t0  = (int*)(ws + OFF_ORDT0);
  int* ord_len = (int*)(ws + OFF_ORDLEN);
  int* nseg    = (int*)(ws + OFF_NSEG);
  float* fcpart= (float*)(ws + OFF_FCPART);
  float* outp = (float*)d_out;

  prep_kernel<<<9649, 256, 0, stream>>>(c1w, c2w, c3w, fcw, wih, whh,
                                        w1b, w2b, w3b, fcwb, wihb, whhb,
                                        starts, ord_b, ord_t0, ord_len, nseg);
  conv1_dma<<<4096, 512, 0, stream>>>(obs, w1b, c1b, x1b);
  conv2_dma<<<4096, 512, 0, stream>>>(x1b, w2b, c2b, x2b);
  conv3_dma<<<4096, 256, 0, stream>>>(x2b, w3b, c3b, x3b);
  gemm_mfma<64, 0><<<dim3(8, 32, 8), 256, 0, stream>>>(
      x3b, fcwb, fcb, nullptr, nullptr, nullptr, 2048, 512, 3136, 0, fcpart);
  fc_reduce<<<2048, 256, 0, stream>>>(fcpart, fcb, auxw, auxb, featb, outp);
  gemm_mfma<64, 0><<<dim3(16, 32), 256, 0, stream>>>(
      featb, wihb, bih, bhh, gx, nullptr, 2048, 1024, 512, 0, nullptr);
  lstm_mfma<<<128, 1024, 0, stream>>>(gx, whhb, starts, h0, c0,
                                      ord_b, ord_t0, ord_len, nseg, hseq);
  heads_kernel<<<512, 256, 0, stream>>>(hseq, actions, aw, ab, cw, cb, outp);
}